// Round 4
// baseline (128.325 us; speedup 1.0000x reference)
//
#include <hip/hip_runtime.h>

typedef __bf16 bf16;
typedef __bf16 bf16x8 __attribute__((ext_vector_type(8)));
typedef __bf16 bf16x4 __attribute__((ext_vector_type(4)));
typedef float f32x4 __attribute__((ext_vector_type(4)));

__device__ __forceinline__ f32x4 mfma16(bf16x8 a, bf16x8 b, f32x4 c) {
  return __builtin_amdgcn_mfma_f32_16x16x32_bf16(a, b, c, 0, 0, 0);
}

// async global->LDS 16B; LDS dest is wave-uniform base, lane l writes base+l*16.
__device__ __forceinline__ void gload16(const void* g, void* l) {
  __builtin_amdgcn_global_load_lds(
      (const __attribute__((address_space(1))) void*)g,
      (__attribute__((address_space(3))) void*)(uint32_t)(size_t)l, 16, 0, 0);
}

// ---------------- gating: g = softmax(x@gw+gb); xgb[b][i*8+l] = bf16(x[b,i]*g[b,l]);
// gbuf = g (f32) for the bias epilogue ----------------
__global__ __launch_bounds__(256) void gating_kernel(
    const float* __restrict__ x, const float* __restrict__ gw,
    const float* __restrict__ gb, bf16* __restrict__ xgb,
    float* __restrict__ gbuf) {
  const int b = blockIdx.x, tid = threadIdx.x;
  __shared__ float xs[256];
  __shared__ float gs[8];
  xs[tid] = x[b * 256 + tid];
  __syncthreads();
  if (tid < 8) {
    float acc = gb[tid];
    for (int i = 0; i < 256; ++i) acc += xs[i] * gw[i * 8 + tid];
    gs[tid] = acc;
  }
  __syncthreads();
  if (tid == 0) {
    float m = gs[0];
    for (int l = 1; l < 8; ++l) m = fmaxf(m, gs[l]);
    float s = 0.f, e[8];
    for (int l = 0; l < 8; ++l) { e[l] = expf(gs[l] - m); s += e[l]; }
    float inv = 1.f / s;
    for (int l = 0; l < 8; ++l) gs[l] = e[l] * inv;
  }
  __syncthreads();
  if (tid < 8) gbuf[b * 8 + tid] = gs[tid];
  bf16* dst = xgb + (size_t)b * 2048;
  for (int k = tid; k < 2048; k += 256)
    dst[k] = (bf16)(xs[k >> 3] * gs[k & 7]);
}

// ---------------- merged weight transform: w (CIN,COUT,4,4) -> wp[p][ocp][t*CIN+ic] ----
template <int CIN, int COUT, int COUTP>
__device__ __forceinline__ void cw_one(const float* __restrict__ w,
                                       bf16* __restrict__ wp, int idx) {
  constexpr int K = 4 * CIN;
  int ic = idx & (CIN - 1);
  int t = (idx / CIN) & 3;
  int oc = (idx / K) % COUTP;
  int p = idx / (K * COUTP);
  bf16 v = (bf16)0.f;
  if (oc < COUT) {
    int py = p >> 1, px = p & 1, tyi = t >> 1, txi = t & 1;
    int ky = py == 0 ? (tyi ? 3 : 1) : (tyi ? 2 : 0);
    int kx = px == 0 ? (txi ? 3 : 1) : (txi ? 2 : 0);
    v = (bf16)w[((ic * COUT + oc) * 4 + ky) * 4 + kx];
  }
  wp[idx] = v;
}

__global__ __launch_bounds__(256) void convert_w_all(
    const float* __restrict__ w1, bf16* __restrict__ w1p,
    const float* __restrict__ w2, bf16* __restrict__ w2p,
    const float* __restrict__ w3, bf16* __restrict__ w3p) {
  int idx = blockIdx.x * 256 + threadIdx.x;
  if (idx < 131072) cw_one<128, 64, 64>(w1, w1p, idx);
  else if (idx < 163840) cw_one<64, 32, 32>(w2, w2p, idx - 131072);
  else if (idx < 172032) cw_one<32, 3, 16>(w3, w3p, idx - 163840);
}

// ---------------- merged halo zero ----------------
template <int HP, int WP, int C>
__device__ __forceinline__ void bz_one(bf16* __restrict__ buf, int idx) {
  constexpr int NCELL = 2 * WP + 2 * (HP - 2);
  constexpr int C8 = C / 8;
  int c8 = idx % C8;
  int rem = idx / C8;
  int cell = rem % NCELL;
  int b = rem / NCELL;
  int y, x;
  if (cell < WP) { y = 0; x = cell; }
  else if (cell < 2 * WP) { y = HP - 1; x = cell - WP; }
  else { int r2 = cell - 2 * WP; y = 1 + (r2 >> 1); x = (r2 & 1) ? WP - 1 : 0; }
  bf16x8 z = {};
  *(bf16x8*)(buf + ((size_t)(b * HP + y) * WP + x) * C + c8 * 8) = z;
}

__global__ __launch_bounds__(256) void border_zero_all(
    bf16* __restrict__ h0t, bf16* __restrict__ h1, bf16* __restrict__ h2) {
  int idx = blockIdx.x * 256 + threadIdx.x;
  if (idx < 147456) bz_one<10, 10, 128>(h0t, idx);
  else if (idx < 286720) bz_one<18, 18, 64>(h1, idx - 147456);
  else if (idx < 421888) bz_one<34, 34, 32>(h2, idx - 286720);
}

// ---------------- fused ME GEMM: C[o,b] = bf16(pw[o,:]) . xgb[b,:] + dot(g[b],pb[o]) ----
// Single N-pass: 256 blocks x 32 M-rows, full N=256. 512 thr = 8 waves (wm=wv&1, wn=wv>>1),
// wave tile 16M x 64N. B (xgb) dbuf LDS via swizzled-source gload16; A = coalesced f32
// direct loads + in-register cvt (pw read exactly once from HBM).
__global__ __launch_bounds__(512) void me_gemm_kernel(
    const float* __restrict__ pw, const bf16* __restrict__ xgb,
    const float* __restrict__ pb, const float* __restrict__ gbuf,
    bf16* __restrict__ h0t) {
  __shared__ char sB[65536];  // 2 x (256 rows x 128 B)
  const int tid = threadIdx.x, wv = tid >> 6, l = tid & 63;
  const int lr = l & 15, lkg = l >> 4;
  const int wm = wv & 1, wn = wv >> 1;
  const int oM0 = blockIdx.x * 32;

  // B staging (hoisted): chunk ch = i*512+tid -> row r=ch>>3, 16B slot c=ch&7
  const bf16* bsrc[4];
  int bdst[4];
#pragma unroll
  for (int i = 0; i < 4; ++i) {
    int ch = i * 512 + tid;
    int r = ch >> 3, c = ch & 7;
    int sb = (c * 16) ^ ((r & 7) << 4);
    bsrc[i] = xgb + (size_t)r * 2048 + (sb >> 1);
    bdst[i] = (i * 512 + wv * 64) * 16;
  }
  // A fragment source: row (oM0+wm*16+lr), k offset lkg*8
  const float* pAf = pw + (size_t)(oM0 + wm * 16 + lr) * 2048 + lkg * 8;

  // hoisted swizzled B read offsets
  int raddrB[4][2];
#pragma unroll
  for (int n = 0; n < 4; ++n) {
    int rb = wn * 64 + n * 16 + lr;
#pragma unroll
    for (int ks = 0; ks < 2; ++ks)
      raddrB[n][ks] = rb * 128 + ((ks * 64 + lkg * 16) ^ ((rb & 7) << 4));
  }

  // prologue: stage kt=0
#pragma unroll
  for (int i = 0; i < 4; ++i) gload16(bsrc[i], sB + bdst[i]);
  float4 c0 = *(const float4*)(pAf);
  float4 c1 = *(const float4*)(pAf + 4);
  float4 c2 = *(const float4*)(pAf + 32);
  float4 c3 = *(const float4*)(pAf + 36);

  f32x4 acc[4] = {};
  __syncthreads();
  for (int kt = 0; kt < 32; ++kt) {
    const int cur = (kt & 1) * 32768;
    float4 n0, n1, n2, n3;
    if (kt < 31) {
      const int nb = ((kt + 1) & 1) * 32768;
      const int ke = (kt + 1) * 64;
#pragma unroll
      for (int i = 0; i < 4; ++i) gload16(bsrc[i] + ke, sB + nb + bdst[i]);
      n0 = *(const float4*)(pAf + ke);
      n1 = *(const float4*)(pAf + ke + 4);
      n2 = *(const float4*)(pAf + ke + 32);
      n3 = *(const float4*)(pAf + ke + 36);
    }
    bf16x8 af[2];
    af[0][0] = (bf16)c0.x; af[0][1] = (bf16)c0.y; af[0][2] = (bf16)c0.z; af[0][3] = (bf16)c0.w;
    af[0][4] = (bf16)c1.x; af[0][5] = (bf16)c1.y; af[0][6] = (bf16)c1.z; af[0][7] = (bf16)c1.w;
    af[1][0] = (bf16)c2.x; af[1][1] = (bf16)c2.y; af[1][2] = (bf16)c2.z; af[1][3] = (bf16)c2.w;
    af[1][4] = (bf16)c3.x; af[1][5] = (bf16)c3.y; af[1][6] = (bf16)c3.z; af[1][7] = (bf16)c3.w;
#pragma unroll
    for (int ks = 0; ks < 2; ++ks)
#pragma unroll
      for (int n = 0; n < 4; ++n) {
        bf16x8 bv = *(const bf16x8*)(sB + cur + raddrB[n][ks]);
        acc[n] = mfma16(af[ks], bv, acc[n]);
      }
    if (kt < 31) { c0 = n0; c1 = n1; c2 = n2; c3 = n3; }
    __syncthreads();
  }

  // epilogue: + dot(g[b], pb[o]) -> h0t padded channels-last
  float4 g0[4], g1[4];
#pragma unroll
  for (int n = 0; n < 4; ++n) {
    int b = wn * 64 + n * 16 + lr;
    g0[n] = *(const float4*)(gbuf + b * 8);
    g1[n] = *(const float4*)(gbuf + b * 8 + 4);
  }
#pragma unroll
  for (int r = 0; r < 4; ++r) {
    int o = oM0 + wm * 16 + lkg * 4 + r;
    float4 p0 = *(const float4*)(pb + o * 8);
    float4 p1 = *(const float4*)(pb + o * 8 + 4);
    int cch = o >> 6, y = (o >> 3) & 7, xx = o & 7;
#pragma unroll
    for (int n = 0; n < 4; ++n) {
      int b = wn * 64 + n * 16 + lr;
      float bias = g0[n].x * p0.x + g0[n].y * p0.y + g0[n].z * p0.z + g0[n].w * p0.w +
                   g1[n].x * p1.x + g1[n].y * p1.y + g1[n].z * p1.z + g1[n].w * p1.w;
      h0t[((size_t)(b * 10 + y + 1) * 10 + xx + 1) * 128 + cch] = (bf16)(acc[n][r] + bias);
    }
  }
}

// ---------------- conv-transpose: LDS-staged input patch (+ weights for conv2/3) -------
template <int CIN, int H, int YB, int COUTP, int WM, int NF, int SWM,
          bool WLDS, int INIT, int WIT, bool RELU, bool F32OUT, int SIN_SZ, int SW_SZ>
__global__ __launch_bounds__(256) void convt_kernel(
    const bf16* __restrict__ in, const bf16* __restrict__ wp,
    const float* __restrict__ bias, bf16* __restrict__ out,
    float* __restrict__ fout) {
  constexpr int W = H, WROW = W + 2, ROWB = CIN * 2, GRS = ROWB / 16;
  constexpr int LGR = (GRS == 16) ? 4 : (GRS == 8) ? 3 : 2;
  constexpr int LW = (W == 8) ? 3 : (W == 16) ? 4 : 5;
  constexpr int K = 4 * CIN;
  constexpr int CHUNKS = (YB + 2) * WROW * GRS;
  constexpr int WGR = K / 8;
  __shared__ char sIn[SIN_SZ];
  __shared__ char sW[SW_SZ];

  const int tid = threadIdx.x, wv = tid >> 6, l = tid & 63;
  const int nyb = H / YB;
  const int img = blockIdx.x / nyb, y0 = (blockIdx.x % nyb) * YB;
  const int p = blockIdx.y, py = p >> 1, px = p & 1;

#pragma unroll
  for (int it = 0; it < INIT; ++it) {
    int t = it * 256 + tid;
    int tc = t < CHUNKS ? t : CHUNKS - 1;
    int pix = tc >> LGR, cc = tc & (GRS - 1);
    int ly = pix / WROW, lx = pix % WROW;
    int sb = (cc * 16) ^ ((pix & SWM) << 4);
    gload16(in + ((size_t)((img * (H + 2) + y0 + ly) * (W + 2) + lx)) * CIN + (sb >> 1),
            sIn + it * 4096 + wv * 1024);
  }
  if constexpr (WLDS) {
#pragma unroll
    for (int it = 0; it < WIT; ++it) {
      int t = it * 256 + tid;
      int oc = t / WGR, cc = t % WGR;
      int sb = (cc * 16) ^ ((oc & 7) << 4);
      gload16(wp + (size_t)(p * COUTP + oc) * K + (sb >> 1), sW + it * 4096 + wv * 1024);
    }
  }
  __syncthreads();

  const int lr = l & 15, lkg = l >> 4;
  const int wm = wv & (WM - 1), wn = wv / WM;
  int pcen[2];
#pragma unroll
  for (int m = 0; m < 2; ++m) {
    int r = wm * 32 + m * 16 + lr;
    pcen[m] = ((r >> LW) + 1) * WROW + (r & (W - 1)) + 1;
  }

  f32x4 acc[2][NF] = {};
#pragma unroll 4
  for (int kk = 0; kk < K; kk += 32) {
    const int t4 = kk / CIN;
    const int tyi = t4 >> 1, txi = t4 & 1;
    const int dy = (py == 0) ? (tyi ? -1 : 0) : (tyi ? 0 : 1);
    const int dx = (px == 0) ? (txi ? -1 : 0) : (txi ? 0 : 1);
    const int icb = (kk % CIN) * 2 + lkg * 16;
    bf16x8 av[2], bv[NF];
#pragma unroll
    for (int m = 0; m < 2; ++m) {
      int pixd = pcen[m] + dy * WROW + dx;
      av[m] = *(const bf16x8*)(sIn + pixd * ROWB + (icb ^ ((pixd & SWM) << 4)));
    }
#pragma unroll
    for (int n = 0; n < NF; ++n) {
      int oc = (wn * NF + n) * 16 + lr;
      if constexpr (WLDS) {
        int kb = kk * 2 + lkg * 16;
        bv[n] = *(const bf16x8*)(sW + oc * (K * 2) + (kb ^ ((oc & 7) << 4)));
      } else {
        bv[n] = *(const bf16x8*)(wp + (size_t)(p * COUTP + oc) * K + kk + lkg * 8);
      }
    }
#pragma unroll
    for (int m = 0; m < 2; ++m)
#pragma unroll
      for (int n = 0; n < NF; ++n) acc[m][n] = mfma16(av[m], bv[n], acc[m][n]);
  }

#pragma unroll
  for (int m = 0; m < 2; ++m)
#pragma unroll
    for (int r4 = 0; r4 < 4; ++r4) {
      int r = wm * 32 + m * 16 + lkg * 4 + r4;
      int yy = r >> LW, xx = r & (W - 1);
      int oy = 2 * (y0 + yy) + py, ox = 2 * xx + px;
#pragma unroll
      for (int n = 0; n < NF; ++n) {
        int oc = (wn * NF + n) * 16 + lr;
        float v = acc[m][n][r4];
        if constexpr (F32OUT) {
          if (oc < 3) fout[((size_t)(img * 3 + oc) * (2 * H) + oy) * (2 * H) + ox] = v + bias[oc];
        } else {
          v += bias[oc];
          if constexpr (RELU) v = fmaxf(v, 0.f);
          out[((size_t)(img * (2 * H + 2) + oy + 1) * (2 * H + 2) + ox + 1) * COUTP + oc] = (bf16)v;
        }
      }
    }
}

// ---------------- launch ----------------
extern "C" void kernel_launch(void* const* d_in, const int* in_sizes, int n_in,
                              void* d_out, int out_size, void* d_ws, size_t ws_size,
                              hipStream_t stream) {
  const float* x  = (const float*)d_in[0];
  const float* gw = (const float*)d_in[1];
  const float* gb = (const float*)d_in[2];
  const float* pw = (const float*)d_in[3];
  const float* pb = (const float*)d_in[4];
  const float* w1 = (const float*)d_in[5];
  const float* b1 = (const float*)d_in[6];
  const float* w2 = (const float*)d_in[7];
  const float* b2 = (const float*)d_in[8];
  const float* w3 = (const float*)d_in[9];
  const float* b3 = (const float*)d_in[10];
  float* outp = (float*)d_out;

  char* ws = (char*)d_ws;
  bf16*  xgb  = (bf16*)(ws + 0);          // 1,048,576
  float* gbuf = (float*)(ws + 1048576);   // 8,192
  bf16*  h0t  = (bf16*)(ws + 1056768);    // 6,553,600
  bf16*  w1p  = (bf16*)(ws + 7610368);    // 262,144
  bf16*  h1   = (bf16*)(ws + 7872512);    // 10,616,832
  bf16*  w2p  = (bf16*)(ws + 18489344);   // 65,536
  bf16*  h2   = (bf16*)(ws + 18554880);   // 18,939,904
  bf16*  w3p  = (bf16*)(ws + 37494784);   // 16,384

  border_zero_all<<<1648, 256, 0, stream>>>(h0t, h1, h2);
  gating_kernel<<<256, 256, 0, stream>>>(x, gw, gb, xgb, gbuf);
  convert_w_all<<<672, 256, 0, stream>>>(w1, w1p, w2, w2p, w3, w3p);

  me_gemm_kernel<<<256, 512, 0, stream>>>(pw, xgb, pb, gbuf, h0t);

  convt_kernel<128, 8, 8, 64, 2, 2, 7, false, 7, 0, true, false, 28672, 16>
      <<<dim3(256, 4), 256, 0, stream>>>(h0t, w1p, b1, h1, nullptr);
  convt_kernel<64, 16, 8, 32, 4, 2, 7, true, 6, 4, true, false, 24576, 16384>
      <<<dim3(512, 4), 256, 0, stream>>>(h1, w2p, b2, h2, nullptr);
  convt_kernel<32, 32, 4, 16, 4, 1, 3, true, 4, 1, false, true, 16384, 4096>
      <<<dim3(2048, 4), 256, 0, stream>>>(h2, w3p, b3, nullptr, outp);
}